// Round 3
// baseline (47.302 us; speedup 1.0000x reference)
//
#include <hip/hip_runtime.h>

#define N_ATOMS 100000
#define KNBR    16
#define EPSF    1e-12f
#define BLOCK   128
#define CAP     8            // max compacted 3-body neighbors (E[cnt]~0.06, P(>8) ~ 1e-13)
#define FRCP(x) __builtin_amdgcn_rcpf(x)

// Pack coords+element into one float4 per atom (gather = 1 dwordx4 instead of 4 loads);
// also zero the output accumulator (runs before sw_main via stream order).
__global__ __launch_bounds__(256) void sw_pack(const float* __restrict__ coords,
                                               const int* __restrict__ elems,
                                               float4* __restrict__ pk,
                                               float* __restrict__ out) {
    const int i = blockIdx.x * 256 + threadIdx.x;
    if (i == 0) out[0] = 0.0f;
    if (i < N_ATOMS) {
        pk[i] = make_float4(coords[3 * i + 0], coords[3 * i + 1], coords[3 * i + 2],
                            __int_as_float(elems[i]));
    }
}

__global__ __launch_bounds__(BLOCK) void sw_main(
    const float4* __restrict__ pk, const int4* __restrict__ nbr4,
    const float* __restrict__ Ap, const float* __restrict__ Bp,
    const float* __restrict__ pp, const float* __restrict__ qp,
    const float* __restrict__ sigp, const float* __restrict__ gamp,
    const float* __restrict__ cutp, const float* __restrict__ lamp,
    const float* __restrict__ cb0p, const float* __restrict__ cjkp,
    float* __restrict__ out)
{
    __shared__ float4 comp[CAP][BLOCK];       // compacted 3-body-eligible neighbors (rel. coords + rij)
    __shared__ float wave_part[BLOCK / 64];

    const int tid = threadIdx.x;
    const int i   = blockIdx.x * BLOCK + tid;

    float acc = 0.0f;

    if (i < N_ATOMS) {
        const float4 pi = pk[i];
        const float xi = pi.x, yi = pi.y, zi = pi.z;
        const int   ei = __float_as_int(pi.w);

        // tiny parameter tables -> registers (uniform -> scalar loads)
        const float c0 = cutp[0], c1 = cutp[1], c2 = cutp[2];
        const float s0 = sigp[0], s1 = sigp[1], s2 = sigp[2];
        const float A0 = Ap[0],  A1 = Ap[1],  A2 = Ap[2];
        const float B0 = Bp[0],  B1 = Bp[1],  B2 = Bp[2];
        const float p0 = pp[0],  p1 = pp[1],  p2 = pp[2];
        const float q0 = qp[0],  q1 = qp[1],  q2 = qp[2];
        const float g1 = gamp[1];
        const float lam_i = lamp[ei];
        const float cb0_i = cb0p[ei];
        const float cjk2_i = cjkp[ei] * cjkp[ei];
        // this instance has p==5, q==0 -> sr^p = sr^5 (3 muls), sr^q = 1
        const bool fastpq = (p0 == 5.f && p1 == 5.f && p2 == 5.f &&
                             q0 == 0.f && q1 == 0.f && q2 == 0.f);

        // neighbor indices: 4x int4, coalesced-ish (64B/lane stride, L1 absorbs)
        const int4 n0 = nbr4[i * 4 + 0];
        const int4 n1 = nbr4[i * 4 + 1];
        const int4 n2 = nbr4[i * 4 + 2];
        const int4 n3 = nbr4[i * 4 + 3];

        int   cnt = 0;
        float e2  = 0.0f;

        auto body = [&](int nj) {
            const float4 pj = pk[nj];                 // single dwordx4 gather (L2-resident)
            const float dx = pj.x - xi, dy = pj.y - yi, dz = pj.z - zi;
            const float r2 = fmaxf(dx * dx + dy * dy + dz * dz, EPSF);
            const int   ej = __float_as_int(pj.w);
            const int   ij = ei + ej;
            const float cut = (ij == 0) ? c0 : ((ij == 1) ? c1 : c2);
            if (r2 < cut * cut) {
                const float rij = sqrtf(r2);
                const float sg  = (ij == 0) ? s0 : ((ij == 1) ? s1 : s2);
                const float Aij = (ij == 0) ? A0 : ((ij == 1) ? A1 : A2);
                const float Bij = (ij == 0) ? B0 : ((ij == 1) ? B1 : B2);
                const float sr  = sg * FRCP(rij);
                float srp, srq;
                if (fastpq) {
                    const float sr2 = sr * sr;
                    srp = sr2 * sr2 * sr;  srq = 1.0f;
                } else {
                    const float pij = (ij == 0) ? p0 : ((ij == 1) ? p1 : p2);
                    const float qij = (ij == 0) ? q0 : ((ij == 1) ? q1 : q2);
                    srp = powf(sr, pij);   srq = powf(sr, qij);
                }
                e2 += Aij * (Bij * srp - srq) * __expf(sg * FRCP(rij - cut));
                if (ej != ei && cnt < CAP) {          // 3-body eligible (=> ij==1, cut==c1)
                    comp[cnt][tid] = make_float4(dx, dy, dz, rij);
                    ++cnt;
                }
            }
        };
        body(n0.x); body(n0.y); body(n0.z); body(n0.w);
        body(n1.x); body(n1.y); body(n1.z); body(n1.w);
        body(n2.x); body(n2.y); body(n2.z); body(n2.w);
        body(n3.x); body(n3.y); body(n3.z); body(n3.w);

        acc = 0.5f * e2;

        // 3-body over compacted neighbors; symmetric in (j,k); no sqrt needed
        for (int a = 0; a + 1 < cnt; ++a) {
            const float4 pa = comp[a][tid];
            const float  ra = pa.w;
            const float  ea = g1 * FRCP(ra - c1);
            for (int b = a + 1; b < cnt; ++b) {
                const float4 pb = comp[b][tid];
                const float ddx = pa.x - pb.x, ddy = pa.y - pb.y, ddz = pa.z - pb.z;
                const float rjk2 = fmaxf(ddx * ddx + ddy * ddy + ddz * ddz, EPSF);
                if (rjk2 < cjk2_i) {
                    const float rb   = pb.w;
                    const float cosv = (ra * ra + rb * rb - rjk2) * 0.5f * FRCP(ra * rb);
                    const float dcs  = cosv - cb0_i;
                    acc += lam_i * __expf(ea + g1 * FRCP(rb - c1)) * dcs * dcs;
                }
            }
        }
    }

    // wave reduce (64 lanes) then block reduce, one atomic per block
    for (int o = 32; o > 0; o >>= 1) acc += __shfl_down(acc, o);
    const int wid  = tid >> 6;
    const int lane = tid & 63;
    if (lane == 0) wave_part[wid] = acc;
    __syncthreads();
    if (tid == 0) {
        float s = 0.0f;
        for (int w = 0; w < BLOCK / 64; ++w) s += wave_part[w];
        atomicAdd(out, s);
    }
}

extern "C" void kernel_launch(void* const* d_in, const int* in_sizes, int n_in,
                              void* d_out, int out_size, void* d_ws, size_t ws_size,
                              hipStream_t stream) {
    const float* coords = (const float*)d_in[0];
    const float* A      = (const float*)d_in[1];
    const float* B      = (const float*)d_in[2];
    const float* p      = (const float*)d_in[3];
    const float* q      = (const float*)d_in[4];
    const float* sigma  = (const float*)d_in[5];
    const float* gamma  = (const float*)d_in[6];
    const float* cutoff = (const float*)d_in[7];
    const float* lam    = (const float*)d_in[8];
    const float* cb0    = (const float*)d_in[9];
    const float* cjk    = (const float*)d_in[10];
    const int*   elems  = (const int*)d_in[11];
    const int*   nbr    = (const int*)d_in[12];
    float* out = (float*)d_out;

    float4* pk = (float4*)d_ws;   // 100000 * 16 B = 1.6 MB scratch

    sw_pack<<<(N_ATOMS + 255) / 256, 256, 0, stream>>>(coords, elems, pk, out);
    sw_main<<<(N_ATOMS + BLOCK - 1) / BLOCK, BLOCK, 0, stream>>>(
        pk, (const int4*)nbr, A, B, p, q, sigma, gamma, cutoff, lam, cb0, cjk, out);
}